// Round 7
// baseline (94.496 us; speedup 1.0000x reference)
//
#include <hip/hip_runtime.h>

#define NPATCH 16384
#define NDB    16384
#define WS9    9
#define KP     16               // K padded 9 -> 16 for 32x32x16 MFMA
#define JCH    32               // db chunks (grid.y)
#define CHUNK  (NDB / JCH)      // 512 rows per chunk
#define TILES  (CHUNK / 32)     // 16 j-tiles per chunk
// Split-bf16 cosmax error vs numpy fp32 path <= ~6e-6. Band +-2e-5 keeps 3x
// margin; band population ~= 80 patches over 64 classify blocks -> in-block
// recheck is ~1-2 entries per block.
#define BAND_LO 0.89998f
#define BAND_HI 0.90002f
#define COPY_BLOCKS 144         // NDB*9/4/256 float4-copy blocks

typedef short bf16x8 __attribute__((ext_vector_type(8)));
typedef float f32x16 __attribute__((ext_vector_type(16)));

#define MAX3(a,b,c) fmaxf(fmaxf((a),(b)),(c))

// numpy-order norm of 9 elements: sqrt(pairwise-8 + remainder), no contraction.
__device__ __forceinline__ float np_norm9(const float* v) {
#pragma clang fp contract(off)
    float q0 = v[0] * v[0], q1 = v[1] * v[1], q2 = v[2] * v[2], q3 = v[3] * v[3];
    float q4 = v[4] * v[4], q5 = v[5] * v[5], q6 = v[6] * v[6], q7 = v[7] * v[7];
    float q8 = v[8] * v[8];
    float s = ((q0 + q1) + (q2 + q3)) + ((q4 + q5) + (q6 + q7));
    s = s + q8;
    return sqrtf(s);
}

// fp32 -> bf16 RTNE (no NaN inputs here), and back
__device__ __forceinline__ unsigned short f2bf(float x) {
    unsigned u = __float_as_uint(x);
    return (unsigned short)((u + 0x7fffu + ((u >> 16) & 1u)) >> 16);
}
__device__ __forceinline__ float bf2f(unsigned short h) {
    return __uint_as_float(((unsigned)h) << 16);
}

// split a row of 9 (already in registers), normalize, split to bf16 hi/lo,
// K-pad to 16, pack 2x int4 per array. MATH IDENTICAL to the proven
// stage_row (absmax=0 in all prior rounds) — only the load path changed.
__device__ __forceinline__ void split_row(const float* v,
                                          unsigned short* dh, unsigned short* dl) {
    float inv = 1.0f / np_norm9(v);
    unsigned short h[KP], l[KP];
#pragma unroll
    for (int k = 0; k < KP; k++) {
        float x = (k < WS9) ? v[k] * inv : 0.0f;
        h[k] = f2bf(x);
        l[k] = f2bf(x - bf2f(h[k]));
    }
    int hw[8], lw[8];
#pragma unroll
    for (int k = 0; k < 8; k++) {
        hw[k] = (int)h[2 * k] | ((int)h[2 * k + 1] << 16);
        lw[k] = (int)l[2 * k] | ((int)l[2 * k + 1] << 16);
    }
    ((int4*)dh)[0] = make_int4(hw[0], hw[1], hw[2], hw[3]);
    ((int4*)dh)[1] = make_int4(hw[4], hw[5], hw[6], hw[7]);
    ((int4*)dl)[0] = make_int4(lw[0], lw[1], lw[2], lw[3]);
    ((int4*)dl)[1] = make_int4(lw[4], lw[5], lw[6], lw[7]);
}

// K1: fused prep + phase1 — R6 body with ONE change: COALESCED input
// staging. Old path: 27 scalar dword loads/thread at 36B lane-stride ->
// ~36 64B-segments per VMEM instr -> ~4000 cyc/CU of TA serialization per
// block generation (G13's scalar-load mistake, fp32 form; present in every
// prior variant). New path: float4/float2 coalesced loads (8 instr/thread,
// ~4 segments each) -> raw rows into the SAME LDS that later holds frags
// (raw -> regs -> barrier -> frag write), identical split math from regs.
__global__ __launch_bounds__(256) void k_phase1(const float* __restrict__ patches,
                                                const float* __restrict__ db,
                                                float* __restrict__ partial) {
    // hi frags in lower half, lo frags in upper half of each region; the raw
    // staging reuses the same bytes (raw db = 18432 B <= 32768 B region).
    __shared__ __align__(16) unsigned short s_d[2 * CHUNK * KP];   // 32 KB
    __shared__ __align__(16) unsigned short s_p[2 * 256 * KP];     // 16 KB

    int jbase = blockIdx.y * CHUNK;
    int ibase = blockIdx.x * 256;
    int tid = (int)threadIdx.x;

    // ---- coalesced raw loads (all issued up front, independent)
    const float4* gdb4 = (const float4*)(db + (size_t)jbase * WS9);      // 1152 f4
    const float2* gdb2 = (const float2*)(db + (size_t)jbase * WS9);      // 2304 f2
    const float4* gpt4 = (const float4*)(patches + (size_t)ibase * WS9); // 576 f4
    const float*  gpt1 = patches + (size_t)ibase * WS9;
    float4 rd0 = gdb4[0 * 256 + tid];
    float4 rd1 = gdb4[1 * 256 + tid];
    float4 rd2 = gdb4[2 * 256 + tid];
    float4 rd3 = gdb4[3 * 256 + tid];
    float2 rd4 = gdb2[2048 + tid];            // floats [4096, 4608)
    float4 rp0 = gpt4[0 * 256 + tid];
    float4 rp1 = gpt4[1 * 256 + tid];
    float  rp2 = gpt1[2048 + tid];            // floats [2048, 2304)

    float* rawd = (float*)s_d;
    float* rawp = (float*)s_p;
    ((float4*)rawd)[0 * 256 + tid] = rd0;
    ((float4*)rawd)[1 * 256 + tid] = rd1;
    ((float4*)rawd)[2 * 256 + tid] = rd2;
    ((float4*)rawd)[3 * 256 + tid] = rd3;
    ((float2*)rawd)[2048 + tid] = rd4;
    ((float4*)rawp)[0 * 256 + tid] = rp0;
    ((float4*)rawp)[1 * 256 + tid] = rp1;
    rawp[2048 + tid] = rp2;
    __syncthreads();

    // ---- each thread pulls its rows from LDS raw (stride 9 across lanes:
    // 9 coprime 32 -> ~2 lanes/bank, free)
    float vdb0[WS9], vdb1[WS9], vpt[WS9];
#pragma unroll
    for (int k = 0; k < WS9; k++) vdb0[k] = rawd[(0 * 256 + tid) * WS9 + k];
#pragma unroll
    for (int k = 0; k < WS9; k++) vdb1[k] = rawd[(1 * 256 + tid) * WS9 + k];
#pragma unroll
    for (int k = 0; k < WS9; k++) vpt[k] = rawp[tid * WS9 + k];
    __syncthreads();   // all raw reads done before frag writes overwrite

    // ---- identical split math, frag writes into the same regions
    split_row(vdb0, &s_d[(0 * 256 + tid) * KP], &s_d[CHUNK * KP + (0 * 256 + tid) * KP]);
    split_row(vdb1, &s_d[(1 * 256 + tid) * KP], &s_d[CHUNK * KP + (1 * 256 + tid) * KP]);
    split_row(vpt,  &s_p[tid * KP],             &s_p[256 * KP + tid * KP]);
    __syncthreads();

    int lane = tid & 63;
    int wave = tid >> 6;
    int col = lane & 31;
    int half = lane >> 5;
    int i0 = ibase + wave * 64;

    const bf16x8* Ph = (const bf16x8*)s_p;                 // hi frags
    const bf16x8* Pl = (const bf16x8*)(s_p + 256 * KP);    // lo frags
    bf16x8 b_hi0 = Ph[(wave * 64 + col) * 2 + half];
    bf16x8 b_lo0 = Pl[(wave * 64 + col) * 2 + half];
    bf16x8 b_hi1 = Ph[(wave * 64 + 32 + col) * 2 + half];
    bf16x8 b_lo1 = Pl[(wave * 64 + 32 + col) * 2 + half];

    const bf16x8* Ah = (const bf16x8*)s_d;
    const bf16x8* Al = (const bf16x8*)(s_d + CHUNK * KP);

    f32x16 zc = {0.f,0.f,0.f,0.f,0.f,0.f,0.f,0.f,0.f,0.f,0.f,0.f,0.f,0.f,0.f,0.f};
    float rm0 = -3.0e38f, rm1 = -3.0e38f;

#pragma unroll 2
    for (int t = 0; t < TILES; ++t) {
        bf16x8 a_h = Ah[(t * 32 + col) * 2 + half];
        bf16x8 a_l = Al[(t * 32 + col) * 2 + half];
        f32x16 acc0 = __builtin_amdgcn_mfma_f32_32x32x16_bf16(a_h, b_hi0, zc, 0, 0, 0);
        acc0 = __builtin_amdgcn_mfma_f32_32x32x16_bf16(a_h, b_lo0, acc0, 0, 0, 0);
        acc0 = __builtin_amdgcn_mfma_f32_32x32x16_bf16(a_l, b_hi0, acc0, 0, 0, 0);
        f32x16 acc1 = __builtin_amdgcn_mfma_f32_32x32x16_bf16(a_h, b_hi1, zc, 0, 0, 0);
        acc1 = __builtin_amdgcn_mfma_f32_32x32x16_bf16(a_h, b_lo1, acc1, 0, 0, 0);
        acc1 = __builtin_amdgcn_mfma_f32_32x32x16_bf16(a_l, b_hi1, acc1, 0, 0, 0);
        // max3-fusable tree (max associative: same result as serial chain)
        {
            float u0 = MAX3(acc0[0],  acc0[1],  acc0[2]);
            float u1 = MAX3(acc0[3],  acc0[4],  acc0[5]);
            float u2 = MAX3(acc0[6],  acc0[7],  acc0[8]);
            float u3 = MAX3(acc0[9],  acc0[10], acc0[11]);
            float u4 = MAX3(acc0[12], acc0[13], acc0[14]);
            float u5 = MAX3(u0, u1, acc0[15]);
            float u6 = MAX3(u2, u3, u4);
            rm0 = MAX3(u5, u6, rm0);
        }
        {
            float u0 = MAX3(acc1[0],  acc1[1],  acc1[2]);
            float u1 = MAX3(acc1[3],  acc1[4],  acc1[5]);
            float u2 = MAX3(acc1[6],  acc1[7],  acc1[8]);
            float u3 = MAX3(acc1[9],  acc1[10], acc1[11]);
            float u4 = MAX3(acc1[12], acc1[13], acc1[14]);
            float u5 = MAX3(u0, u1, acc1[15]);
            float u6 = MAX3(u2, u3, u4);
            rm1 = MAX3(u5, u6, rm1);
        }
    }
    rm0 = fmaxf(rm0, __shfl_xor(rm0, 32, 64));
    rm1 = fmaxf(rm1, __shfl_xor(rm1, 32, 64));
    int ti = half ? (i0 + 32 + col) : (i0 + col);
    partial[(size_t)blockIdx.y * NPATCH + ti] = half ? rm1 : rm0;
}

// K2: merged finish (verbatim R6, passed absmax=0). Blocks [0,144): db->out
// float4 copy. Blocks [144,208): classify 256 patches (max over 32 chunk-
// partials), write definite rows, recheck band entries inline with the
// exact numpy-mirror path.
__global__ __launch_bounds__(256) void k_finish(const float* __restrict__ patches,
                                                const float* __restrict__ db,
                                                const float* __restrict__ partial,
                                                float* __restrict__ out) {
    int b = blockIdx.x;
    if (b < COPY_BLOCKS) {
        int e = b * 256 + threadIdx.x;          // 36864 float4 = 147456 floats
        ((float4*)out)[e] = ((const float4*)db)[e];
        return;
    }
    __shared__ int s_bn;
    __shared__ int s_blist[256];
    __shared__ float sp[WS9];
    __shared__ float snp;
    __shared__ int shit;

    int tid = (int)threadIdx.x;
    int i = (b - COPY_BLOCKS) * 256 + tid;
    if (tid == 0) s_bn = 0;
    __syncthreads();

    float cosmax = partial[i];
#pragma unroll
    for (int c = 1; c < JCH; c++)
        cosmax = fmaxf(cosmax, partial[(size_t)c * NPATCH + i]);
    if (cosmax >= BAND_LO && cosmax < BAND_HI) {
        int idx = atomicAdd(&s_bn, 1);
        s_blist[idx] = i;                       // rechecked below
    } else {
        int hit = (cosmax >= BAND_HI) ? 1 : 0;
#pragma unroll
        for (int k = 0; k < WS9; k++)
            out[(size_t)(NDB + i) * WS9 + k] = hit ? 0.0f : patches[(size_t)i * WS9 + k];
    }
    __syncthreads();
    int nb = s_bn;

    // exact numpy-mirror recheck (typically 0-2 entries per block)
    for (int e = 0; e < nb; e++) {
        int bi = s_blist[e];
        if (tid == 0) {
            float p[WS9];
            for (int k = 0; k < WS9; k++) { p[k] = patches[(size_t)bi * WS9 + k]; sp[k] = p[k]; }
            snp = np_norm9(p);
            shit = 0;
        }
        __syncthreads();
        float p[WS9];
#pragma unroll
        for (int k = 0; k < WS9; k++) p[k] = sp[k];
        float npn = snp;
        int hit = 0;
        for (int j = tid; j < NDB; j += 256) {
            float d[WS9];
#pragma unroll
            for (int k = 0; k < WS9; k++) d[k] = db[(size_t)j * WS9 + k];
            float dot = 0.0f;
#pragma unroll
            for (int k = 0; k < WS9; k++) dot = fmaf(p[k], d[k], dot);
            float nd = np_norm9(d);
            float cs = dot / (npn * nd);          // IEEE fp32 divide
            if (!((double)cs < 0.9)) hit = 1;     // numpy promotes to f64
        }
        if (hit) atomicOr(&shit, 1);
        __syncthreads();
        int m = shit;
        if (tid < WS9)
            out[(size_t)(NDB + bi) * WS9 + tid] = m ? 0.0f : sp[tid];
        __syncthreads();
    }
}

extern "C" void kernel_launch(void* const* d_in, const int* in_sizes, int n_in,
                              void* d_out, int out_size, void* d_ws, size_t ws_size,
                              hipStream_t stream) {
    const float* patches = (const float*)d_in[0];  // [16384][9]
    const float* db      = (const float*)d_in[1];  // [16384][9]
    float* out = (float*)d_out;                    // [32768][9]

    // ws layout: partial (JCH*NPATCH f32 = 2 MB)
    float* partial = (float*)d_ws;

    k_phase1<<<dim3(NPATCH / 256, JCH), dim3(256), 0, stream>>>(patches, db, partial);
    k_finish<<<dim3(COPY_BLOCKS + NPATCH / 256), dim3(256), 0, stream>>>(
        patches, db, partial, out);
}

// Round 8
// 93.444 us; speedup vs baseline: 1.0113x; 1.0113x over previous
//
#include <hip/hip_runtime.h>

#define NPATCH 16384
#define NDB    16384
#define WS9    9
#define KP     16               // K padded 9 -> 16 for 32x32x16 MFMA
#define NSL    8                // j-slices (grid.y); partial has 8 rows now
#define SLICE  (NDB / NSL)      // 2048 db rows per block
#define CHUNK  512              // rows per double-buffer step
#define NCH    (SLICE / CHUNK)  // 4 chunk iterations per block
#define TILES  (CHUNK / 32)     // 16 j-tiles per chunk
// Split-bf16 cosmax error vs numpy fp32 path <= ~6e-6. Band +-2e-5 keeps 3x
// margin; band population ~= 80 patches over 64 classify blocks -> in-block
// recheck is ~1-2 entries per block.
#define BAND_LO 0.89998f
#define BAND_HI 0.90002f
#define COPY_BLOCKS 144         // NDB*9/4/256 float4-copy blocks

typedef short bf16x8 __attribute__((ext_vector_type(8)));
typedef float f32x16 __attribute__((ext_vector_type(16)));

#define MAX3(a,b,c) fmaxf(fmaxf((a),(b)),(c))

// numpy-order norm of 9 elements: sqrt(pairwise-8 + remainder), no contraction.
__device__ __forceinline__ float np_norm9(const float* v) {
#pragma clang fp contract(off)
    float q0 = v[0] * v[0], q1 = v[1] * v[1], q2 = v[2] * v[2], q3 = v[3] * v[3];
    float q4 = v[4] * v[4], q5 = v[5] * v[5], q6 = v[6] * v[6], q7 = v[7] * v[7];
    float q8 = v[8] * v[8];
    float s = ((q0 + q1) + (q2 + q3)) + ((q4 + q5) + (q6 + q7));
    s = s + q8;
    return sqrtf(s);
}

// fp32 -> bf16 RTNE (no NaN inputs here), and back
__device__ __forceinline__ unsigned short f2bf(float x) {
    unsigned u = __float_as_uint(x);
    return (unsigned short)((u + 0x7fffu + ((u >> 16) & 1u)) >> 16);
}
__device__ __forceinline__ float bf2f(unsigned short h) {
    return __uint_as_float(((unsigned)h) << 16);
}

// split a row of 9 (in registers): normalize, split bf16 hi/lo, K-pad to 16,
// pack 2x int4 per array. Math identical to the proven staging (absmax=0).
__device__ __forceinline__ void split_row(const float* v,
                                          unsigned short* dh, unsigned short* dl) {
    float inv = 1.0f / np_norm9(v);
    unsigned short h[KP], l[KP];
#pragma unroll
    for (int k = 0; k < KP; k++) {
        float x = (k < WS9) ? v[k] * inv : 0.0f;
        h[k] = f2bf(x);
        l[k] = f2bf(x - bf2f(h[k]));
    }
    int hw[8], lw[8];
#pragma unroll
    for (int k = 0; k < 8; k++) {
        hw[k] = (int)h[2 * k] | ((int)h[2 * k + 1] << 16);
        lw[k] = (int)l[2 * k] | ((int)l[2 * k + 1] << 16);
    }
    ((int4*)dh)[0] = make_int4(hw[0], hw[1], hw[2], hw[3]);
    ((int4*)dh)[1] = make_int4(hw[4], hw[5], hw[6], hw[7]);
    ((int4*)dl)[0] = make_int4(lw[0], lw[1], lw[2], lw[3]);
    ((int4*)dl)[1] = make_int4(lw[4], lw[5], lw[6], lw[7]);
}

// K1: single-generation, prefetched phase1. Grid 64x8 = 512 blocks = exactly
// 2 resident/CU (80 KB LDS) — no block generations, no re-staging convoy.
// Each block: stage 256 patches once; loop 4 chunks of 512 db rows with
// double-buffered LDS, where chunk c+1's raw rows are loaded to REGISTERS
// before chunk c's K-loop (MFMA covers the global latency even if HBM is
// contended by the poison-fill drain) and split+written after it. Same MFMA
// sequence per tile; per-patch max accumulates across chunks in-register
// (fmax exact+associative) -> bit-identical cosmax, absmax 0.
__global__ __launch_bounds__(256) void k_phase1(const float* __restrict__ patches,
                                                const float* __restrict__ db,
                                                float* __restrict__ partial) {
    __shared__ __align__(16) unsigned short s_pnh[256 * KP];        // 8 KB
    __shared__ __align__(16) unsigned short s_pnl[256 * KP];        // 8 KB
    __shared__ __align__(16) unsigned short s_dh[2][CHUNK * KP];    // 32 KB
    __shared__ __align__(16) unsigned short s_dl[2][CHUNK * KP];    // 32 KB

    int tid = (int)threadIdx.x;
    int jbase = blockIdx.y * SLICE;
    int ibase = blockIdx.x * 256;

    // ---- stage 256 patches once (proven scalar path; R7 showed load-path
    // shape is neutral)
    {
        float v[WS9];
        const float* g = patches + (size_t)(ibase + tid) * WS9;
#pragma unroll
        for (int k = 0; k < WS9; k++) v[k] = g[k];
        split_row(v, &s_pnh[tid * KP], &s_pnl[tid * KP]);
    }

    // ---- chunk 0: raw -> regs -> split -> buf 0
    float va[WS9], vb[WS9];
    {
        const float* g0 = db + (size_t)(jbase + tid) * WS9;
        const float* g1 = db + (size_t)(jbase + 256 + tid) * WS9;
#pragma unroll
        for (int k = 0; k < WS9; k++) { va[k] = g0[k]; vb[k] = g1[k]; }
        split_row(va, &s_dh[0][tid * KP], &s_dl[0][tid * KP]);
        split_row(vb, &s_dh[0][(256 + tid) * KP], &s_dl[0][(256 + tid) * KP]);
    }
    __syncthreads();

    int lane = tid & 63;
    int wave = tid >> 6;
    int col = lane & 31;
    int half = lane >> 5;
    int i0 = ibase + wave * 64;

    const bf16x8* Ph = (const bf16x8*)s_pnh;   // 2 frags per 16-elem row
    const bf16x8* Pl = (const bf16x8*)s_pnl;
    bf16x8 b_hi0 = Ph[(wave * 64 + col) * 2 + half];
    bf16x8 b_lo0 = Pl[(wave * 64 + col) * 2 + half];
    bf16x8 b_hi1 = Ph[(wave * 64 + 32 + col) * 2 + half];
    bf16x8 b_lo1 = Pl[(wave * 64 + 32 + col) * 2 + half];

    f32x16 zc = {0.f,0.f,0.f,0.f,0.f,0.f,0.f,0.f,0.f,0.f,0.f,0.f,0.f,0.f,0.f,0.f};
    float rm0 = -3.0e38f, rm1 = -3.0e38f;

    for (int c = 0; c < NCH; c++) {
        int cur = c & 1;
        // prefetch next chunk's raw rows into registers BEFORE the K-loop;
        // the 16-tile MFMA loop below covers the global-load latency.
        if (c < NCH - 1) {
            const float* p0 = db + (size_t)(jbase + (c + 1) * CHUNK + tid) * WS9;
            const float* p1 = db + (size_t)(jbase + (c + 1) * CHUNK + 256 + tid) * WS9;
#pragma unroll
            for (int k = 0; k < WS9; k++) { va[k] = p0[k]; vb[k] = p1[k]; }
        }

        const bf16x8* Ah = (const bf16x8*)s_dh[cur];
        const bf16x8* Al = (const bf16x8*)s_dl[cur];
#pragma unroll 2
        for (int t = 0; t < TILES; ++t) {
            bf16x8 a_h = Ah[(t * 32 + col) * 2 + half];
            bf16x8 a_l = Al[(t * 32 + col) * 2 + half];
            f32x16 acc0 = __builtin_amdgcn_mfma_f32_32x32x16_bf16(a_h, b_hi0, zc, 0, 0, 0);
            acc0 = __builtin_amdgcn_mfma_f32_32x32x16_bf16(a_h, b_lo0, acc0, 0, 0, 0);
            acc0 = __builtin_amdgcn_mfma_f32_32x32x16_bf16(a_l, b_hi0, acc0, 0, 0, 0);
            f32x16 acc1 = __builtin_amdgcn_mfma_f32_32x32x16_bf16(a_h, b_hi1, zc, 0, 0, 0);
            acc1 = __builtin_amdgcn_mfma_f32_32x32x16_bf16(a_h, b_lo1, acc1, 0, 0, 0);
            acc1 = __builtin_amdgcn_mfma_f32_32x32x16_bf16(a_l, b_hi1, acc1, 0, 0, 0);
            {
                float u0 = MAX3(acc0[0],  acc0[1],  acc0[2]);
                float u1 = MAX3(acc0[3],  acc0[4],  acc0[5]);
                float u2 = MAX3(acc0[6],  acc0[7],  acc0[8]);
                float u3 = MAX3(acc0[9],  acc0[10], acc0[11]);
                float u4 = MAX3(acc0[12], acc0[13], acc0[14]);
                float u5 = MAX3(u0, u1, acc0[15]);
                float u6 = MAX3(u2, u3, u4);
                rm0 = MAX3(u5, u6, rm0);
            }
            {
                float u0 = MAX3(acc1[0],  acc1[1],  acc1[2]);
                float u1 = MAX3(acc1[3],  acc1[4],  acc1[5]);
                float u2 = MAX3(acc1[6],  acc1[7],  acc1[8]);
                float u3 = MAX3(acc1[9],  acc1[10], acc1[11]);
                float u4 = MAX3(acc1[12], acc1[13], acc1[14]);
                float u5 = MAX3(u0, u1, acc1[15]);
                float u6 = MAX3(u2, u3, u4);
                rm1 = MAX3(u5, u6, rm1);
            }
        }

        // split+write next chunk into the other buffer (after this chunk's
        // reads; barrier below publishes it for the next iteration)
        if (c < NCH - 1) {
            split_row(va, &s_dh[cur ^ 1][tid * KP], &s_dl[cur ^ 1][tid * KP]);
            split_row(vb, &s_dh[cur ^ 1][(256 + tid) * KP], &s_dl[cur ^ 1][(256 + tid) * KP]);
        }
        __syncthreads();
    }

    rm0 = fmaxf(rm0, __shfl_xor(rm0, 32, 64));
    rm1 = fmaxf(rm1, __shfl_xor(rm1, 32, 64));
    int ti = half ? (i0 + 32 + col) : (i0 + col);
    partial[(size_t)blockIdx.y * NPATCH + ti] = half ? rm1 : rm0;
}

// K2: merged finish (R6 structure, passed absmax=0; now 8 partial slices).
// Blocks [0,144): db->out float4 copy. Blocks [144,208): classify 256
// patches (max over 8 slice-partials), write definite rows, recheck band
// entries inline with the exact numpy-mirror path.
__global__ __launch_bounds__(256) void k_finish(const float* __restrict__ patches,
                                                const float* __restrict__ db,
                                                const float* __restrict__ partial,
                                                float* __restrict__ out) {
    int b = blockIdx.x;
    if (b < COPY_BLOCKS) {
        int e = b * 256 + threadIdx.x;          // 36864 float4 = 147456 floats
        ((float4*)out)[e] = ((const float4*)db)[e];
        return;
    }
    __shared__ int s_bn;
    __shared__ int s_blist[256];
    __shared__ float sp[WS9];
    __shared__ float snp;
    __shared__ int shit;

    int tid = (int)threadIdx.x;
    int i = (b - COPY_BLOCKS) * 256 + tid;
    if (tid == 0) s_bn = 0;
    __syncthreads();

    float cosmax = partial[i];
#pragma unroll
    for (int c = 1; c < NSL; c++)
        cosmax = fmaxf(cosmax, partial[(size_t)c * NPATCH + i]);
    if (cosmax >= BAND_LO && cosmax < BAND_HI) {
        int idx = atomicAdd(&s_bn, 1);
        s_blist[idx] = i;                       // rechecked below
    } else {
        int hit = (cosmax >= BAND_HI) ? 1 : 0;
#pragma unroll
        for (int k = 0; k < WS9; k++)
            out[(size_t)(NDB + i) * WS9 + k] = hit ? 0.0f : patches[(size_t)i * WS9 + k];
    }
    __syncthreads();
    int nb = s_bn;

    // exact numpy-mirror recheck (typically 0-2 entries per block)
    for (int e = 0; e < nb; e++) {
        int bi = s_blist[e];
        if (tid == 0) {
            float p[WS9];
            for (int k = 0; k < WS9; k++) { p[k] = patches[(size_t)bi * WS9 + k]; sp[k] = p[k]; }
            snp = np_norm9(p);
            shit = 0;
        }
        __syncthreads();
        float p[WS9];
#pragma unroll
        for (int k = 0; k < WS9; k++) p[k] = sp[k];
        float npn = snp;
        int hit = 0;
        for (int j = tid; j < NDB; j += 256) {
            float d[WS9];
#pragma unroll
            for (int k = 0; k < WS9; k++) d[k] = db[(size_t)j * WS9 + k];
            float dot = 0.0f;
#pragma unroll
            for (int k = 0; k < WS9; k++) dot = fmaf(p[k], d[k], dot);
            float nd = np_norm9(d);
            float cs = dot / (npn * nd);          // IEEE fp32 divide
            if (!((double)cs < 0.9)) hit = 1;     // numpy promotes to f64
        }
        if (hit) atomicOr(&shit, 1);
        __syncthreads();
        int m = shit;
        if (tid < WS9)
            out[(size_t)(NDB + bi) * WS9 + tid] = m ? 0.0f : sp[tid];
        __syncthreads();
    }
}

extern "C" void kernel_launch(void* const* d_in, const int* in_sizes, int n_in,
                              void* d_out, int out_size, void* d_ws, size_t ws_size,
                              hipStream_t stream) {
    const float* patches = (const float*)d_in[0];  // [16384][9]
    const float* db      = (const float*)d_in[1];  // [16384][9]
    float* out = (float*)d_out;                    // [32768][9]

    // ws layout: partial (NSL*NPATCH f32 = 512 KB)
    float* partial = (float*)d_ws;

    k_phase1<<<dim3(NPATCH / 256, NSL), dim3(256), 0, stream>>>(patches, db, partial);
    k_finish<<<dim3(COPY_BLOCKS + NPATCH / 256), dim3(256), 0, stream>>>(
        patches, db, partial, out);
}